// Round 13
// baseline (67.311 us; speedup 1.0000x reference)
//
#include <hip/hip_runtime.h>
#include <math.h>

#define IMG_H 512
#define IMG_W 512
#define CH    3
#define TILE_W 16
#define TILE_H 32                // two 16-row halves
#define HALF  16
#define PAD   2
#define TP    20                 // padded per-half tile: 20 rows x 20 cols

typedef float v2f __attribute__((ext_vector_type(2)));
typedef float v4f __attribute__((ext_vector_type(4)));

#if __has_builtin(__builtin_amdgcn_exp2f)
#define EXP2(x) __builtin_amdgcn_exp2f(x)
#else
#define EXP2(x) exp2f(x)
#endif

#if __has_builtin(__builtin_amdgcn_rcpf)
#define RCP(x) __builtin_amdgcn_rcpf(x)
#else
#define RCP(x) (1.0f / (x))
#endif

#define LOV(a) __builtin_shufflevector(a, a, 0, 1)
#define HIV(a) __builtin_shufflevector(a, a, 2, 3)

__device__ __forceinline__ int reflect_idx(int i, int n) {
    i = (i < 0) ? -i : i;
    i = (i >= n) ? (2 * n - 2 - i) : i;
    return i;
}

__global__ __launch_bounds__(128)
void bilateral_kernel(const float* __restrict__ in, float* __restrict__ out) {
    // 4 px/thread: rows (r0, r0+1) in half A and half B (=A+16), same column.
    // Channels interleaved across halves so every v2f is a natural VGPR pair:
    //   planeP[r][c] = (xA, xB, yA, yB)   planeQ[r][c] = (zA, zB, wA, wB)
    // 6-row x 5-col window serves both row-centers -> 16 b128/px (was 26).
    // 20x20-float4, wave lane-groups on rows 4 apart: proven conflict-free.
    __shared__ v4f planeP[TP][TP];
    __shared__ v4f planeQ[TP][TP];

    const float S = sqrtf(312.5f * 1.44269504088896f);  // compile-time folded

    const int b  = blockIdx.z;
    const int by = blockIdx.y * TILE_H;
    const int bx = blockIdx.x * TILE_W;
    const int tx = threadIdx.x;
    const int ty = threadIdx.y;          // 0..7, each owns a row pair per half
    const int tid = ty * TILE_W + tx;

    // Staging: 400 entries, each covers two pixels (padded rows r and r+16).
    for (int i = tid; i < TP * TP; i += TILE_W * 8) {
        const int r  = i / TP;
        const int cc = i - r * TP;
        const int gyA = reflect_idx(by + r - PAD, IMG_H);
        const int gyB = reflect_idx(by + HALF + r - PAD, IMG_H);
        const int gx  = reflect_idx(bx + cc - PAD, IMG_W);
        const float* pA = in + ((size_t)(b * IMG_H + gyA) * IMG_W + gx) * CH;
        const float* pB = in + ((size_t)(b * IMG_H + gyB) * IMG_W + gx) * CH;
        const float a0 = pA[0] * S, a1 = pA[1] * S, a2 = pA[2] * S;
        const float e0 = pB[0] * S, e1 = pB[1] * S, e2 = pB[2] * S;
        const float wA = -fmaf(a0, a0, fmaf(a1, a1, a2 * a2));
        const float wB = -fmaf(e0, e0, fmaf(e1, e1, e2 * e2));
        planeP[r][cc] = (v4f){ a0, e0, a1, e1 };
        planeQ[r][cc] = (v4f){ a2, e2, wA, wB };
    }
    __syncthreads();

    // Row-pair permutation: wave 0 (ty 0..3) -> r0 {0,4,8,12}; wave 1 -> {2,6,10,14}.
    const int r0 = ((ty & 3) << 2) | ((ty >> 2) << 1);

    // log2 of normalized 1-D gaussian weights, index min(d, 4-d).
    const float CW[3] = { -4.1978935f, -2.0338538f, -1.3125121f };

    const v4f* Pb = &planeP[r0][tx];
    const v4f* Qb = &planeQ[r0][tx];

    // Centers j=0,1 at window offsets (2+j, 2).
    const v4f cP0 = Pb[2 * TP + 2], cQ0 = Qb[2 * TP + 2];
    const v4f cP1 = Pb[3 * TP + 2], cQ1 = Qb[3 * TP + 2];
    const v2f c2x0 = LOV(cP0) + LOV(cP0), c2y0 = HIV(cP0) + HIV(cP0);
    const v2f c2z0 = LOV(cQ0) + LOV(cQ0), cw0  = HIV(cQ0);
    const v2f c2x1 = LOV(cP1) + LOV(cP1), c2y1 = HIV(cP1) + HIV(cP1);
    const v2f c2z1 = LOV(cQ1) + LOV(cQ1), cw1  = HIV(cQ1);

    v2f nx0 = (v2f){0.f,0.f}, ny0 = nx0, nz0 = nx0, nd0 = nx0;
    v2f nx1 = nx0, ny1 = nx0, nz1 = nx0, nd1 = nx0;

#define TAP(c2x, c2y, c2z, cw, KC, nx, ny, nz, nd)                         \
    do {                                                                   \
        v2f t = __builtin_elementwise_fma(sz, c2z, sw);                    \
        t = __builtin_elementwise_fma(sy, c2y, t);                         \
        t = __builtin_elementwise_fma(sx, c2x, t);                         \
        t = t + cw;                                                        \
        t = t + (v2f){ KC, KC };                                           \
        const v2f w = (v2f){ EXP2(t.x), EXP2(t.y) };                       \
        nx = __builtin_elementwise_fma(w, sx, nx);                         \
        ny = __builtin_elementwise_fma(w, sy, ny);                         \
        nz = __builtin_elementwise_fma(w, sz, nz);                         \
        nd = nd + w;                                                       \
    } while (0)

    #pragma unroll
    for (int r = 0; r < 6; ++r) {
        const int iy0 = (r < 3) ? r : 4 - r;          // valid when r <= 4
        const int dy1 = r - 1;
        const int iy1 = (dy1 < 3) ? dy1 : 4 - dy1;    // valid when r >= 1
        #pragma unroll
        for (int k = 0; k < 5; ++k) {
            const int ix = (k < 3) ? k : 4 - k;
            const v4f P = Pb[r * TP + k];
            const v4f Q = Qb[r * TP + k];
            const v2f sx = LOV(P), sy = HIV(P);
            const v2f sz = LOV(Q), sw = HIV(Q);
            if (r <= 4) {
                const float KC0 = CW[iy0] + CW[ix];
                TAP(c2x0, c2y0, c2z0, cw0, KC0, nx0, ny0, nz0, nd0);
            }
            if (r >= 1) {
                const float KC1 = CW[iy1] + CW[ix];
                TAP(c2x1, c2y1, c2z1, cw1, KC1, nx1, ny1, nz1, nd1);
            }
        }
    }
#undef TAP

    const int xcol = bx + tx;
    #pragma unroll
    for (int j = 0; j < 2; ++j) {
        const v2f nx = j ? nx1 : nx0, ny = j ? ny1 : ny0;
        const v2f nz = j ? nz1 : nz0, nd = j ? nd1 : nd0;
        {
            const float inv = RCP(nd.x * S);
            float* dst = out + ((size_t)(b * IMG_H + by + r0 + j) * IMG_W + xcol) * CH;
            dst[0] = fminf(fmaxf(nx.x * inv, 0.0f), 1.0f);
            dst[1] = fminf(fmaxf(ny.x * inv, 0.0f), 1.0f);
            dst[2] = fminf(fmaxf(nz.x * inv, 0.0f), 1.0f);
        }
        {
            const float inv = RCP(nd.y * S);
            float* dst = out + ((size_t)(b * IMG_H + by + HALF + r0 + j) * IMG_W + xcol) * CH;
            dst[0] = fminf(fmaxf(nx.y * inv, 0.0f), 1.0f);
            dst[1] = fminf(fmaxf(ny.y * inv, 0.0f), 1.0f);
            dst[2] = fminf(fmaxf(nz.y * inv, 0.0f), 1.0f);
        }
    }
}

extern "C" void kernel_launch(void* const* d_in, const int* in_sizes, int n_in,
                              void* d_out, int out_size, void* d_ws, size_t ws_size,
                              hipStream_t stream) {
    const float* in = (const float*)d_in[0];
    float* out = (float*)d_out;
    const int B = in_sizes[0] / (IMG_H * IMG_W * CH);   // 16

    dim3 block(TILE_W, 8, 1);
    dim3 grid(IMG_W / TILE_W, IMG_H / TILE_H, B);       // 32 x 16 x 16
    bilateral_kernel<<<grid, block, 0, stream>>>(in, out);
}